// Round 8
// baseline (124.491 us; speedup 1.0000x reference)
//
#include <hip/hip_runtime.h>

#define HID 2048
#define NE 64
#define NTOK 32768        // GROUPS * TOKENS = 4 * 8192
#define CAP 160
#define GAP_THR 0.01f

typedef unsigned short u16;
typedef short bf16x8 __attribute__((ext_vector_type(8)));
typedef float f32x16 __attribute__((ext_vector_type(16)));

typedef __attribute__((address_space(1))) const void gvoid;
typedef __attribute__((address_space(3))) void lvoid;
#define GLOAD_LDS16(gp, lp) \
    __builtin_amdgcn_global_load_lds((gvoid*)(gp), (lvoid*)(lp), 16, 0, 0)

// fp32 -> bf16 hi (truncate) + bf16 lo (truncate of exact remainder).
static __device__ __forceinline__ void cvt8(const float4& a, const float4& b,
                                            bf16x8& hi, bf16x8& lo) {
    float f[8] = {a.x, a.y, a.z, a.w, b.x, b.y, b.z, b.w};
#pragma unroll
    for (int j = 0; j < 8; ++j) {
        const unsigned u = __float_as_uint(f[j]);
        const unsigned h = u >> 16;
        const float r = f[j] - __uint_as_float(h << 16);   // exact
        hi[j] = (short)h;
        lo[j] = (short)(__float_as_uint(r) >> 16);
    }
}

// ---------------------------------------------------------------------------
// K0: split W into bf16 hi/lo, fragment-major: step S owns 4KB [h0|h1|l0|l1],
// each chunk 1KB = lane*16B.  S = global K-step = k0/16.
// ---------------------------------------------------------------------------
__global__ void k_wconv(const float* __restrict__ W, u16* __restrict__ Wfrag)
{
    const int idx = blockIdx.x * 256 + threadIdx.x;   // 0..16383
    if (idx >= NE * (HID / 8)) return;
    const int e  = idx >> 8;          // expert 0..63
    const int k0 = (idx & 255) * 8;
    const int S    = k0 >> 4;
    const int khal = (k0 >> 3) & 1;
    const int lane = (e & 31) + khal * 32;

    bf16x8 hi, lo;
    const float4 a = *(const float4*)(W + (size_t)e * HID + k0);
    const float4 b = *(const float4*)(W + (size_t)e * HID + k0 + 4);
    cvt8(a, b, hi, lo);

    u16* base = Wfrag + (size_t)S * 2048 + (size_t)(e >> 5) * 512 + lane * 8;
    *(bf16x8*)(base)        = hi;     // chunk (e>>5)
    *(bf16x8*)(base + 1024) = lo;     // chunk 2+(e>>5)
}

// ---------------------------------------------------------------------------
// K1: logits via 3-term bf16-split MFMA, LDS-staged A, counted-vmcnt pipeline.
// Block = 256 thr = 4 waves, 32 tokens.  A chunk = [32 rows][128 floats],
// TRIPLE-buffered: iter c issues DMA(c+2) -> ~2 iterations of HBM flight.
// Per iter: vmcnt(4) [own DMA(c) retired, c+1/c+2 stay in flight] -> raw
// s_barrier -> LOADW (before DMA: FIFO vmcnt keeps A in flight) -> DMA(c+2)
// -> compute.  NO vmcnt(0) drain in the loop (T3/T4).
// XOR-swizzle on the GLOBAL source (LDS dest linear, granule = sg^row);
// compute reads granule g0^trow -> conflict-free b128.
// ---------------------------------------------------------------------------
__global__ __launch_bounds__(256, 3) void k_logits(
    const float* __restrict__ A, const u16* __restrict__ Wfrag,
    const float* __restrict__ bias,
    float* __restrict__ logits, float* __restrict__ probsmax,
    int* __restrict__ choice, int* __restrict__ idx2o, float* __restrict__ gapo)
{
    __shared__ float smem[3 * 4096];      // 48 KB: A triple-buffer; reused as lacc
    const int tid  = threadIdx.x;
    const int lane = tid & 63;
    const int kq   = __builtin_amdgcn_readfirstlane(tid >> 6);  // 0..3 uniform
    const int tok0 = blockIdx.x * 32;
    const int trow = lane & 31;           // token row (B-col)
    const int khal = lane >> 5;

    // DMA source: wave kq stages LDS rows [kq*8, kq*8+8); instr i covers rows
    // r0+2i (khal picks the half); lane slot sg holds global granule sg^row.
    const int sg = lane & 31;
    const int r0 = kq * 8 + khal;
#define GPTR(i) (A + (size_t)(tok0 + r0 + 2*(i)) * HID + ((sg ^ (r0 + 2*(i))) << 2))
    const float* gp0 = GPTR(0);
    const float* gp1 = GPTR(1);
    const float* gp2 = GPTR(2);
    const float* gp3 = GPTR(3);
#undef GPTR

    const u16* wbase = Wfrag + lane * 8;  // per-lane 16B, coalesced 1KB/instr

    f32x16 acc0, acc1;
#pragma unroll
    for (int r = 0; r < 16; ++r) { acc0[r] = 0.0f; acc1[r] = 0.0f; }

#define MFMA_ __builtin_amdgcn_mfma_f32_32x32x16_bf16
#define DMA(BUF) {                                                        \
    float* dst = smem + (BUF) * 4096 + kq * 1024;                         \
    GLOAD_LDS16(gp0, dst);                                                \
    GLOAD_LDS16(gp1, dst + 256);                                          \
    GLOAD_LDS16(gp2, dst + 512);                                          \
    GLOAD_LDS16(gp3, dst + 768);                                          \
    gp0 += 128; gp1 += 128; gp2 += 128; gp3 += 128; }

    // prologue: fill pipeline with chunks 0 and 1
    DMA(0)
    DMA(1)

#pragma unroll 1
    for (int c = 0; c < 16; ++c) {
        // own DMA(c) retired; DMA(c+1), DMA(c+2) stay in flight
        asm volatile("s_waitcnt vmcnt(4)" ::: "memory");
        __builtin_amdgcn_s_barrier();
        __builtin_amdgcn_sched_barrier(0);

        // W frags for this chunk — issued BEFORE next DMA (FIFO: their
        // compiler-inserted waits then never drain the A pipeline).
        bf16x8 wh0[2], wh1[2], wl0[2], wl1[2];
#pragma unroll
        for (int s = 0; s < 2; ++s) {
            const u16* wp = wbase + (size_t)(c * 8 + kq * 2 + s) * 2048;
            wh0[s] = *(const bf16x8*)(wp);
            wh1[s] = *(const bf16x8*)(wp + 512);
            wl0[s] = *(const bf16x8*)(wp + 1024);
            wl1[s] = *(const bf16x8*)(wp + 1536);
        }
        __builtin_amdgcn_sched_barrier(0);
        if (c < 14) DMA((c + 2) % 3)      // buf held c-1; released by barrier
        __builtin_amdgcn_sched_barrier(0);

        const float* base2 = smem + (c % 3) * 4096 + trow * 128;
#pragma unroll
        for (int s = 0; s < 2; ++s) {
            const int g0 = (kq * 2 + s) * 4 + khal * 2;
            const float4 va = *(const float4*)(base2 + ((g0 ^ trow) << 2));
            const float4 vb = *(const float4*)(base2 + (((g0 + 1) ^ trow) << 2));
            bf16x8 ah, al; cvt8(va, vb, ah, al);
            acc0 = MFMA_(wh0[s], ah, acc0, 0, 0, 0);
            acc1 = MFMA_(wh1[s], ah, acc1, 0, 0, 0);
            acc0 = MFMA_(wl0[s], ah, acc0, 0, 0, 0);
            acc1 = MFMA_(wl1[s], ah, acc1, 0, 0, 0);
            acc0 = MFMA_(wh0[s], al, acc0, 0, 0, 0);
            acc1 = MFMA_(wh1[s], al, acc1, 0, 0, 0);
        }
    }
#undef DMA

    __syncthreads();                      // all reads done; reuse smem as lacc

    // ---- epilogue: smem reused as lacc[4][32*65] ----
    {
        float* pl = smem + kq * 2080 + trow * 65;
#pragma unroll
        for (int r = 0; r < 16; ++r) {
            const int er = (r & 3) + 8 * (r >> 2) + 4 * khal;
            pl[er]      = acc0[r];
            pl[32 + er] = acc1[r];
        }
    }
    __syncthreads();

    // split-K reduce (+bias), coalesced logits store, stash row into plane 0
    {
        const int t  = tid >> 3;          // 0..31
        const int e0 = (tid & 7) * 8;
        float v[8];
#pragma unroll
        for (int i = 0; i < 8; ++i) {
            const int o = t * 65 + e0 + i;
            v[i] = smem[o] + smem[2080 + o] + smem[4160 + o] + smem[6240 + o]
                 + bias[e0 + i];
        }
        float* lp = logits + (size_t)(tok0 + t) * NE + e0;
        *(float4*)(lp)     = make_float4(v[0], v[1], v[2], v[3]);
        *(float4*)(lp + 4) = make_float4(v[4], v[5], v[6], v[7]);
#pragma unroll
        for (int i = 0; i < 8; ++i) smem[t * 65 + e0 + i] = v[i];
    }
    __syncthreads();

    // per-token epilogue: top-2 + softmax denominator
    if (tid < 32) {
        const int t = tid;
        float m1 = -3.4e38f, m2 = -3.4e38f;
        int i1 = 0, i2 = 0;
#pragma unroll
        for (int e = 0; e < NE; ++e) {
            const float vv = smem[t * 65 + e];
            if (vv > m1)      { m2 = m1; i2 = i1; m1 = vv; i1 = e; }
            else if (vv > m2) { m2 = vv; i2 = e; }
        }
        float sden = 0.0f;
#pragma unroll
        for (int e = 0; e < NE; ++e)
            sden += __expf(smem[t * 65 + e] - m1);
        const int g2 = tok0 + t;
        probsmax[g2] = 1.0f / sden;       // max prob = exp(0)/sum
        choice[g2]   = i1;
        idx2o[g2]    = i2;
        gapo[g2]     = m1 - m2;
    }
}

// ---------------------------------------------------------------------------
// K1b: fp64 refinement of near-tie argmax, wave-cooperative.
// ---------------------------------------------------------------------------
__global__ __launch_bounds__(64) void k_refine(
    const float* __restrict__ A, const float* __restrict__ W,
    const float* __restrict__ bias,
    int* __restrict__ choice, const int* __restrict__ idx2,
    const float* __restrict__ gap)
{
    const int lane = threadIdx.x;
    const int gt0  = blockIdx.x * 64;
    const int gtl  = gt0 + lane;
    const bool flag = (gap[gtl] < GAP_THR) && (choice[gtl] != idx2[gtl]);
    unsigned long long m = __ballot(flag);
    while (m) {
        const int t = (int)__ffsll((long long)m) - 1;
        m &= m - 1;
        const int gt = gt0 + t;
        const int i1 = choice[gt], i2 = idx2[gt];
        const float* a  = A + (size_t)gt * HID;
        const float* w1 = W + (size_t)i1 * HID;
        const float* w2 = W + (size_t)i2 * HID;
        double d1 = 0.0, d2 = 0.0;
#pragma unroll 4
        for (int h = lane; h < HID; h += 64) {
            const double av = (double)a[h];
            d1 += av * (double)w1[h];
            d2 += av * (double)w2[h];
        }
#pragma unroll
        for (int o = 32; o; o >>= 1) {
            d1 += __shfl_xor(d1, o);
            d2 += __shfl_xor(d2, o);
        }
        if (lane == 0) {
            d1 += (double)bias[i1];
            d2 += (double)bias[i2];
            if (d2 > d1 || (d2 == d1 && i2 < i1)) choice[gt] = i2;
        }
    }
}

// ---------------------------------------------------------------------------
// K2: per-64-token-chunk histogram of expert choices (wave ballot).
// ---------------------------------------------------------------------------
__global__ void k_count(const int* __restrict__ choice, int* __restrict__ cnt)
{
    const int lane  = threadIdx.x & 63;
    const int wave  = threadIdx.x >> 6;
    const int chunk = blockIdx.x * 4 + wave;   // 0..511
    const int gt    = chunk * 64 + lane;
    const int c     = choice[gt];
    int mycnt = 0;
#pragma unroll 1
    for (int e = 0; e < NE; ++e) {
        const unsigned long long m = __ballot(c == e);
        if (lane == e) mycnt = (int)__popcll(m);
    }
    cnt[chunk * 64 + lane] = mycnt;
}

// ---------------------------------------------------------------------------
// K3: exclusive scan of 128 chunk-histograms per group, staged in LDS.
// ---------------------------------------------------------------------------
__global__ __launch_bounds__(256) void k_scan(const int* __restrict__ cnt,
                                              int* __restrict__ off)
{
    __shared__ int s[128 * 64];       // 32 KB
    const int tid  = threadIdx.x;
    const int base = blockIdx.x * 128 * 64;
#pragma unroll
    for (int i = 0; i < 32; ++i)
        s[tid + 256 * i] = cnt[base + tid + 256 * i];
    __syncthreads();
    if (tid < 64) {
        int run = 0;
#pragma unroll 1
        for (int c = 0; c < 128; ++c) {
            const int idx = c * 64 + tid;
            const int v = s[idx];
            s[idx] = run;
            run += v;
        }
    }
    __syncthreads();
#pragma unroll
    for (int i = 0; i < 32; ++i)
        off[base + tid + 256 * i] = s[tid + 256 * i];
}

// ---------------------------------------------------------------------------
// K4: emit expert_index rows (0/1 as fp32) with capacity mask.
// ---------------------------------------------------------------------------
__global__ void k_emit(const int* __restrict__ choice, const int* __restrict__ off,
                       float* __restrict__ eout)
{
    const int lane  = threadIdx.x & 63;
    const int wave  = threadIdx.x >> 6;
    const int chunk = blockIdx.x * 4 + wave;
    const int gt    = chunk * 64 + lane;
    const int c     = choice[gt];
    unsigned long long mymask = 0;
#pragma unroll 1
    for (int e = 0; e < NE; ++e) {
        const unsigned long long m = __ballot(c == e);
        if (c == e) mymask = m;
    }
    const int pre  = (int)__popcll(mymask & ((1ull << lane) - 1ull));
    const int base = off[chunk * 64 + c];
    const float val = (base + pre + 1 <= CAP) ? 1.0f : 0.0f;
    float* op = eout + (size_t)gt * NE;
#pragma unroll
    for (int i = 0; i < 16; ++i) {
        float4 v;
        v.x = (4*i+0 == c) ? val : 0.0f;
        v.y = (4*i+1 == c) ? val : 0.0f;
        v.z = (4*i+2 == c) ? val : 0.0f;
        v.w = (4*i+3 == c) ? val : 0.0f;
        ((float4*)op)[i] = v;
    }
}

// ---------------------------------------------------------------------------
extern "C" void kernel_launch(void* const* d_in, const int* in_sizes, int n_in,
                              void* d_out, int out_size, void* d_ws, size_t ws_size,
                              hipStream_t stream) {
    const float* A = (const float*)d_in[0];   // [4, 8192, 2048]
    const float* W = (const float*)d_in[1];   // [64, 2048]
    const float* b = (const float*)d_in[2];   // [64]

    float* out        = (float*)d_out;
    float* expert_out = out;                        // 2,097,152
    float* probsmax   = out + 2097152;              //    32,768
    float* logits     = out + 2097152 + 32768;      // 2,097,152

    char* ws      = (char*)d_ws;
    int*   choice = (int*)(ws);                 // 128 KB
    int*   idx2   = (int*)(ws + 131072);        // 128 KB
    float* gap    = (float*)(ws + 262144);      // 128 KB
    int*   cnt    = (int*)(ws + 393216);        // 128 KB
    int*   off    = (int*)(ws + 524288);        // 128 KB
    u16*   Wfrag  = (u16*)(ws + 655360);        // 512 KB fragment-major

    hipLaunchKernelGGL(k_wconv, dim3(64), dim3(256), 0, stream, W, Wfrag);
    hipLaunchKernelGGL(k_logits, dim3(1024), dim3(256), 0, stream,
                       A, Wfrag, b, logits, probsmax, choice, idx2, gap);
    hipLaunchKernelGGL(k_refine, dim3(512), dim3(64), 0, stream,
                       A, W, b, choice, idx2, gap);
    hipLaunchKernelGGL(k_count, dim3(128), dim3(256), 0, stream, choice, cnt);
    hipLaunchKernelGGL(k_scan, dim3(4), dim3(256), 0, stream, cnt, off);
    hipLaunchKernelGGL(k_emit, dim3(128), dim3(256), 0, stream, choice, off, expert_out);
}

// Round 9
// 114.724 us; speedup vs baseline: 1.0851x; 1.0851x over previous
//
#include <hip/hip_runtime.h>

#define HID 2048
#define NE 64
#define NTOK 32768        // GROUPS * TOKENS = 4 * 8192
#define CAP 160
#define GAP_THR 0.01f

typedef unsigned short u16;
typedef short bf16x8 __attribute__((ext_vector_type(8)));
typedef float f32x16 __attribute__((ext_vector_type(16)));

typedef __attribute__((address_space(1))) const void gvoid;
typedef __attribute__((address_space(3))) void lvoid;
#define GLOAD_LDS16(gp, lp) \
    __builtin_amdgcn_global_load_lds((gvoid*)(gp), (lvoid*)(lp), 16, 0, 0)

// fp32 -> bf16 hi (truncate) + bf16 lo (truncate of exact remainder).
static __device__ __forceinline__ void cvt8(const float4& a, const float4& b,
                                            bf16x8& hi, bf16x8& lo) {
    float f[8] = {a.x, a.y, a.z, a.w, b.x, b.y, b.z, b.w};
#pragma unroll
    for (int j = 0; j < 8; ++j) {
        const unsigned u = __float_as_uint(f[j]);
        const unsigned h = u >> 16;
        const float r = f[j] - __uint_as_float(h << 16);   // exact
        hi[j] = (short)h;
        lo[j] = (short)(__float_as_uint(r) >> 16);
    }
}

// ---------------------------------------------------------------------------
// K0: split W into bf16 hi/lo, fragment-major: step S (0..127) owns 4KB
// [h0|h1|l0|l1], each chunk 1KB = lane*16B.  S = global K-step = k0/16.
// ---------------------------------------------------------------------------
__global__ void k_wconv(const float* __restrict__ W, u16* __restrict__ Wfrag)
{
    const int idx = blockIdx.x * 256 + threadIdx.x;   // 0..16383
    if (idx >= NE * (HID / 8)) return;
    const int e  = idx >> 8;          // expert 0..63
    const int k0 = (idx & 255) * 8;
    const int S    = k0 >> 4;
    const int khal = (k0 >> 3) & 1;
    const int lane = (e & 31) + khal * 32;

    bf16x8 hi, lo;
    const float4 a = *(const float4*)(W + (size_t)e * HID + k0);
    const float4 b = *(const float4*)(W + (size_t)e * HID + k0 + 4);
    cvt8(a, b, hi, lo);

    u16* base = Wfrag + (size_t)S * 2048 + (size_t)(e >> 5) * 512 + lane * 8;
    *(bf16x8*)(base)        = hi;     // chunk (e>>5)
    *(bf16x8*)(base + 1024) = lo;     // chunk 2+(e>>5)
}

// ---------------------------------------------------------------------------
// K1: logits via 3-term bf16-split MFMA, LDS-staged A, FIFO-aware pipeline.
// Block = 256 thr = 4 waves, 32 tokens.  Chunk = [32 rows][64 floats] (8KB),
// 32 chunks, TRIPLE-buffered (24KB < 33KB lacc floor -> LDS stays 33KB,
// 4 blocks/CU).  Issue order per iter (FIFO-aware — round 8 lesson: a W-reg
// wait retires all OLDER DMAs, so W(c+1) is issued BEFORE DMA(c+2)):
//   vmcnt(6) [retires DMA(c); W(c)+DMA(c+1) stay] -> s_barrier ->
//   W(c+1) regs -> DMA(c+2) -> compute(c)
// Compiler's W(c)-wait = vmcnt(8) leaves DMA(c+1) (newer) in flight ->
// DMA flight ~2 iterations ~ HBM latency.  No vmcnt(0) drain in the loop.
// Wave kq owns K-step kq of each chunk's 4 (split-K, reduced in epilogue).
// XOR-swizzle on the GLOBAL source (LDS linear): slot ^ (row&7).
// ---------------------------------------------------------------------------
__global__ __launch_bounds__(256, 4) void k_logits(
    const float* __restrict__ A, const u16* __restrict__ Wfrag,
    const float* __restrict__ bias,
    float* __restrict__ logits, float* __restrict__ probsmax,
    int* __restrict__ choice, int* __restrict__ idx2o, float* __restrict__ gapo)
{
    __shared__ float smem[8448];          // bufs 3*2048=6144; lacc 8320 floor
    const int tid  = threadIdx.x;
    const int lane = tid & 63;
    const int kq   = __builtin_amdgcn_readfirstlane(tid >> 6);  // 0..3 uniform
    const int tok0 = blockIdx.x * 32;
    const int trow = lane & 31;           // token row (B-col)
    const int khal = lane >> 5;

    // DMA source: wave kq stages LDS rows [kq*8, +8).  Instr A covers rows
    // kq*8+(l>>4), instr B rows kq*8+4+(l>>4); slot (l&15) holds global
    // granule (l&15)^(row&7)  (inverse swizzle on source, LDS linear).
    const int sg16 = lane & 15;
    const int rA   = kq * 8 + (lane >> 4);        // rA & 7 = lane>>4
    const int rB   = rA + 4;
    const float* gpA = A + (size_t)(tok0 + rA) * HID + ((sg16 ^ (rA & 7)) << 2);
    const float* gpB = A + (size_t)(tok0 + rB) * HID + ((sg16 ^ (rB & 7)) << 2);

    const u16* wbase = Wfrag + lane * 8;  // per-lane 16B, coalesced 1KB/instr

    f32x16 acc0, acc1;
#pragma unroll
    for (int r = 0; r < 16; ++r) { acc0[r] = 0.0f; acc1[r] = 0.0f; }

    bf16x8 wA[4], wB[4];                  // two W sets (h0,h1,l0,l1), parity-rotated

#define MFMA_ __builtin_amdgcn_mfma_f32_32x32x16_bf16
#define LOADW(SET, C) {                                                   \
    const u16* wp = wbase + (size_t)((C) * 4 + kq) * 2048;                \
    SET[0] = *(const bf16x8*)(wp);                                        \
    SET[1] = *(const bf16x8*)(wp + 512);                                  \
    SET[2] = *(const bf16x8*)(wp + 1024);                                 \
    SET[3] = *(const bf16x8*)(wp + 1536); }
#define DMA(BUF) {                                                        \
    float* dst = smem + (BUF) * 2048 + kq * 512;                          \
    GLOAD_LDS16(gpA, dst);                                                \
    GLOAD_LDS16(gpB, dst + 256);                                          \
    gpA += 64; gpB += 64; }
#define COMPUTE(BUF, SET) {                                               \
    const float* base2 = smem + (BUF) * 2048 + trow * 64;                 \
    const int g0 = kq * 4 + khal * 2;                                     \
    const float4 va = *(const float4*)(base2 + ((g0 ^ (trow & 7)) << 2)); \
    const float4 vb = *(const float4*)(base2 + (((g0 + 1) ^ (trow & 7)) << 2)); \
    bf16x8 ah, al; cvt8(va, vb, ah, al);                                  \
    acc0 = MFMA_(SET[0], ah, acc0, 0, 0, 0);                              \
    acc1 = MFMA_(SET[1], ah, acc1, 0, 0, 0);                              \
    acc0 = MFMA_(SET[2], ah, acc0, 0, 0, 0);                              \
    acc1 = MFMA_(SET[3], ah, acc1, 0, 0, 0);                              \
    acc0 = MFMA_(SET[0], al, acc0, 0, 0, 0);                              \
    acc1 = MFMA_(SET[1], al, acc1, 0, 0, 0); }
#define ITER(C, USESET, LDSET, VM) {                                      \
    asm volatile("s_waitcnt vmcnt(" #VM ")" ::: "memory");                \
    __builtin_amdgcn_s_barrier();                                         \
    __builtin_amdgcn_sched_barrier(0);                                    \
    LOADW(LDSET, (C) + 1)                                                 \
    DMA(((C) + 2) % 3)                                                    \
    __builtin_amdgcn_sched_barrier(0);                                    \
    COMPUTE((C) % 3, USESET) }

    // prologue: FIFO = [DMA(0), W(0), DMA(1)]
    DMA(0)
    LOADW(wA, 0)
    DMA(1)

#pragma unroll 1
    for (int c = 0; c < 30; c += 2) {
        ITER(c,     wA, wB, 6)
        ITER(c + 1, wB, wA, 6)
    }
    // peeled tail: ITER(30) issues W(31) only; ITER(31) issues nothing
    asm volatile("s_waitcnt vmcnt(6)" ::: "memory");
    __builtin_amdgcn_s_barrier();
    __builtin_amdgcn_sched_barrier(0);
    LOADW(wB, 31)
    __builtin_amdgcn_sched_barrier(0);
    COMPUTE(0, wA)                        // 30 % 3 == 0
    asm volatile("s_waitcnt vmcnt(4)" ::: "memory");
    __builtin_amdgcn_s_barrier();
    __builtin_amdgcn_sched_barrier(0);
    COMPUTE(1, wB)                        // 31 % 3 == 1
#undef ITER
#undef COMPUTE
#undef DMA
#undef LOADW

    __syncthreads();                      // all reads done; reuse smem as lacc

    // ---- epilogue: smem reused as lacc[4][32*65] ----
    {
        float* pl = smem + kq * 2080 + trow * 65;
#pragma unroll
        for (int r = 0; r < 16; ++r) {
            const int er = (r & 3) + 8 * (r >> 2) + 4 * khal;
            pl[er]      = acc0[r];
            pl[32 + er] = acc1[r];
        }
    }
    __syncthreads();

    // split-K reduce (+bias), coalesced logits store, stash row into plane 0
    {
        const int t  = tid >> 3;          // 0..31
        const int e0 = (tid & 7) * 8;
        float v[8];
#pragma unroll
        for (int i = 0; i < 8; ++i) {
            const int o = t * 65 + e0 + i;
            v[i] = smem[o] + smem[2080 + o] + smem[4160 + o] + smem[6240 + o]
                 + bias[e0 + i];
        }
        float* lp = logits + (size_t)(tok0 + t) * NE + e0;
        *(float4*)(lp)     = make_float4(v[0], v[1], v[2], v[3]);
        *(float4*)(lp + 4) = make_float4(v[4], v[5], v[6], v[7]);
#pragma unroll
        for (int i = 0; i < 8; ++i) smem[t * 65 + e0 + i] = v[i];
    }
    __syncthreads();

    // per-token epilogue: top-2 + softmax denominator
    if (tid < 32) {
        const int t = tid;
        float m1 = -3.4e38f, m2 = -3.4e38f;
        int i1 = 0, i2 = 0;
#pragma unroll
        for (int e = 0; e < NE; ++e) {
            const float vv = smem[t * 65 + e];
            if (vv > m1)      { m2 = m1; i2 = i1; m1 = vv; i1 = e; }
            else if (vv > m2) { m2 = vv; i2 = e; }
        }
        float sden = 0.0f;
#pragma unroll
        for (int e = 0; e < NE; ++e)
            sden += __expf(smem[t * 65 + e] - m1);
        const int g2 = tok0 + t;
        probsmax[g2] = 1.0f / sden;       // max prob = exp(0)/sum
        choice[g2]   = i1;
        idx2o[g2]    = i2;
        gapo[g2]     = m1 - m2;
    }
}

// ---------------------------------------------------------------------------
// K1b: fp64 refinement of near-tie argmax, wave-cooperative.
// ---------------------------------------------------------------------------
__global__ __launch_bounds__(64) void k_refine(
    const float* __restrict__ A, const float* __restrict__ W,
    const float* __restrict__ bias,
    int* __restrict__ choice, const int* __restrict__ idx2,
    const float* __restrict__ gap)
{
    const int lane = threadIdx.x;
    const int gt0  = blockIdx.x * 64;
    const int gtl  = gt0 + lane;
    const bool flag = (gap[gtl] < GAP_THR) && (choice[gtl] != idx2[gtl]);
    unsigned long long m = __ballot(flag);
    while (m) {
        const int t = (int)__ffsll((long long)m) - 1;
        m &= m - 1;
        const int gt = gt0 + t;
        const int i1 = choice[gt], i2 = idx2[gt];
        const float* a  = A + (size_t)gt * HID;
        const float* w1 = W + (size_t)i1 * HID;
        const float* w2 = W + (size_t)i2 * HID;
        double d1 = 0.0, d2 = 0.0;
#pragma unroll 4
        for (int h = lane; h < HID; h += 64) {
            const double av = (double)a[h];
            d1 += av * (double)w1[h];
            d2 += av * (double)w2[h];
        }
#pragma unroll
        for (int o = 32; o; o >>= 1) {
            d1 += __shfl_xor(d1, o);
            d2 += __shfl_xor(d2, o);
        }
        if (lane == 0) {
            d1 += (double)bias[i1];
            d2 += (double)bias[i2];
            if (d2 > d1 || (d2 == d1 && i2 < i1)) choice[gt] = i2;
        }
    }
}

// ---------------------------------------------------------------------------
// K2: per-64-token-chunk histogram of expert choices (wave ballot).
// ---------------------------------------------------------------------------
__global__ void k_count(const int* __restrict__ choice, int* __restrict__ cnt)
{
    const int lane  = threadIdx.x & 63;
    const int wave  = threadIdx.x >> 6;
    const int chunk = blockIdx.x * 4 + wave;   // 0..511
    const int gt    = chunk * 64 + lane;
    const int c     = choice[gt];
    int mycnt = 0;
#pragma unroll 1
    for (int e = 0; e < NE; ++e) {
        const unsigned long long m = __ballot(c == e);
        if (lane == e) mycnt = (int)__popcll(m);
    }
    cnt[chunk * 64 + lane] = mycnt;
}

// ---------------------------------------------------------------------------
// K3: exclusive scan of 128 chunk-histograms per group, staged in LDS.
// ---------------------------------------------------------------------------
__global__ __launch_bounds__(256) void k_scan(const int* __restrict__ cnt,
                                              int* __restrict__ off)
{
    __shared__ int s[128 * 64];       // 32 KB
    const int tid  = threadIdx.x;
    const int base = blockIdx.x * 128 * 64;
#pragma unroll
    for (int i = 0; i < 32; ++i)
        s[tid + 256 * i] = cnt[base + tid + 256 * i];
    __syncthreads();
    if (tid < 64) {
        int run = 0;
#pragma unroll 1
        for (int c = 0; c < 128; ++c) {
            const int idx = c * 64 + tid;
            const int v = s[idx];
            s[idx] = run;
            run += v;
        }
    }
    __syncthreads();
#pragma unroll
    for (int i = 0; i < 32; ++i)
        off[base + tid + 256 * i] = s[tid + 256 * i];
}

// ---------------------------------------------------------------------------
// K4: emit expert_index rows (0/1 as fp32) with capacity mask.
// ---------------------------------------------------------------------------
__global__ void k_emit(const int* __restrict__ choice, const int* __restrict__ off,
                       float* __restrict__ eout)
{
    const int lane  = threadIdx.x & 63;
    const int wave  = threadIdx.x >> 6;
    const int chunk = blockIdx.x * 4 + wave;
    const int gt    = chunk * 64 + lane;
    const int c     = choice[gt];
    unsigned long long mymask = 0;
#pragma unroll 1
    for (int e = 0; e < NE; ++e) {
        const unsigned long long m = __ballot(c == e);
        if (c == e) mymask = m;
    }
    const int pre  = (int)__popcll(mymask & ((1ull << lane) - 1ull));
    const int base = off[chunk * 64 + c];
    const float val = (base + pre + 1 <= CAP) ? 1.0f : 0.0f;
    float* op = eout + (size_t)gt * NE;
#pragma unroll
    for (int i = 0; i < 16; ++i) {
        float4 v;
        v.x = (4*i+0 == c) ? val : 0.0f;
        v.y = (4*i+1 == c) ? val : 0.0f;
        v.z = (4*i+2 == c) ? val : 0.0f;
        v.w = (4*i+3 == c) ? val : 0.0f;
        ((float4*)op)[i] = v;
    }
}

// ---------------------------------------------------------------------------
extern "C" void kernel_launch(void* const* d_in, const int* in_sizes, int n_in,
                              void* d_out, int out_size, void* d_ws, size_t ws_size,
                              hipStream_t stream) {
    const float* A = (const float*)d_in[0];   // [4, 8192, 2048]
    const float* W = (const float*)d_in[1];   // [64, 2048]
    const float* b = (const float*)d_in[2];   // [64]

    float* out        = (float*)d_out;
    float* expert_out = out;                        // 2,097,152
    float* probsmax   = out + 2097152;              //    32,768
    float* logits     = out + 2097152 + 32768;      // 2,097,152

    char* ws      = (char*)d_ws;
    int*   choice = (int*)(ws);                 // 128 KB
    int*   idx2   = (int*)(ws + 131072);        // 128 KB
    float* gap    = (float*)(ws + 262144);      // 128 KB
    int*   cnt    = (int*)(ws + 393216);        // 128 KB
    int*   off    = (int*)(ws + 524288);        // 128 KB
    u16*   Wfrag  = (u16*)(ws + 655360);        // 512 KB fragment-major

    hipLaunchKernelGGL(k_wconv, dim3(64), dim3(256), 0, stream, W, Wfrag);
    hipLaunchKernelGGL(k_logits, dim3(1024), dim3(256), 0, stream,
                       A, Wfrag, b, logits, probsmax, choice, idx2, gap);
    hipLaunchKernelGGL(k_refine, dim3(512), dim3(64), 0, stream,
                       A, W, b, choice, idx2, gap);
    hipLaunchKernelGGL(k_count, dim3(128), dim3(256), 0, stream, choice, cnt);
    hipLaunchKernelGGL(k_scan, dim3(4), dim3(256), 0, stream, cnt, off);
    hipLaunchKernelGGL(k_emit, dim3(128), dim3(256), 0, stream, choice, off, expert_out);
}